// Round 8
// baseline (298.457 us; speedup 1.0000x reference)
//
#include <hip/hip_runtime.h>

// LSTMModel: B=4096, T=512, IN=2, H=12, OUT=2, fp32.
// One batch element per wave64; lane = (unit u = lane>>2, gate = lane&3).
// 1024 blocks x 256 threads -> 4096 waves = 4 waves/SIMD.
// v_pk_fma_f32 (tied "+v", 3 parallel chains) for the gate dots.
// h broadcast via per-wave private LDS: predicated ds_write_b32 (12 writer
// lanes -> banks 0-11, conflict-free) + 3x ds_read_b128 readback, ordering
// pinned by compile-time asm memory fences.
// RESIDENCY FIX (r8): weights loaded via VOLATILE scalar loads (cannot be
// re-executed) and pinned by ONE pre-loop asm volatile keep-alive (opaque
// def-point -- LLVM never remats inline asm). r4-r7's VGPR=40 + 77%-vs-44%
// VALUBusy mismatch proved the weight set was rebuilt every step.

namespace {
constexpr int H  = 12;
constexpr int T  = 512;
constexpr float LOG2E = 1.4426950408889634f;

typedef float f2 __attribute__((ext_vector_type(2)));
typedef float f4 __attribute__((ext_vector_type(4)));

__device__ __forceinline__ f2 pkfma(f2 a, f2 b, f2 c) {
    asm("v_pk_fma_f32 %0, %1, %2, %0" : "+v"(c) : "v"(a), "v"(b));
    return c;
}
__device__ __forceinline__ f2 pkmul(f2 a, f2 b) {
    f2 d; asm("v_pk_mul_f32 %0, %1, %2" : "=v"(d) : "v"(a), "v"(b)); return d;
}
__device__ __forceinline__ f2 pkadd(f2 a, f2 b) {
    f2 d; asm("v_pk_add_f32 %0, %1, %2" : "=v"(d) : "v"(a), "v"(b)); return d;
}
__device__ __forceinline__ float exp2_(float x) {
    float r; asm("v_exp_f32 %0, %1" : "=v"(r) : "v"(x)); return r;
}
__device__ __forceinline__ float rcp_(float x) { return __builtin_amdgcn_rcpf(x); }
__device__ __forceinline__ void memfence_() { asm volatile("" ::: "memory"); }
__device__ __forceinline__ float vld(const float* p) {
    return *(const volatile float*)p;   // non-duplicable load
}

template <int CTRL>
__device__ __forceinline__ float dppf(float v) {
    return __int_as_float(__builtin_amdgcn_update_dpp(
        __float_as_int(v), __float_as_int(v), CTRL, 0xF, 0xF, true));
}
constexpr int QP1 = 0x39;  // quad_perm [1,2,3,0]
constexpr int QP2 = 0x4E;  // quad_perm [2,3,0,1]
constexpr int QP3 = 0x93;  // quad_perm [3,0,1,2]
} // namespace

__global__ __launch_bounds__(256, 4) void lstm2_fc_kernel(
    const float* __restrict__ x,      // (4096, 512, 2)
    const float* __restrict__ W_ih0,  // (48, 2)
    const float* __restrict__ W_hh0,  // (48, 12)
    const float* __restrict__ b_ih0,  // (48)
    const float* __restrict__ b_hh0,  // (48)
    const float* __restrict__ W_ih1,  // (48, 12)
    const float* __restrict__ W_hh1,  // (48, 12)
    const float* __restrict__ b_ih1,  // (48)
    const float* __restrict__ b_hh1,  // (48)
    const float* __restrict__ fc_W,   // (2, 12)
    const float* __restrict__ fc_b,   // (2)
    float* __restrict__ out)          // (4096, 2)
{
    const int lane = threadIdx.x & 63;
    const int wid  = __builtin_amdgcn_readfirstlane((int)threadIdx.x >> 6);
    const int b    = blockIdx.x * 4 + wid;       // one element per wave
    const int u    = lane >> 2;                  // unit 0..15 (12 active)
    const int gate = lane & 3;                   // 0:i 1:f 2:g 3:o
    const int uc   = (u < H) ? u : 0;            // clamp idle lanes
    const int r    = gate * H + uc;              // weight row

    // sigmoid for i,f,o; tanh (=2*sigm(2x)-1) for g; exp2 prescale kmul
    // folded into weights & bias.
    const float pre  = (gate == 2) ? 2.0f : 1.0f;
    const float kmul = -LOG2E * pre;
    const float pa   = 1.0f - pre;
    const float km2  = -2.0f * LOG2E;            // for tanh(c)

    // ---- per-wave private LDS: 16 floats per layer per wave ----
    __shared__ __align__(16) float sm[4 * 32];
    float* smb = &sm[wid * 32];
    const bool writer = (gate == 0) && (u < H);
    float* smw0 = smb + uc;                      // layer-0 writer slot (banks 0-11)
    float* smw1 = smb + 16 + uc;                 // layer-1 writer slot

    // ------- prescaled packed weights -> registers (VOLATILE loads) -------
    f2 wx, whh0p[6], wih1p[6], whh1p[6];
    wx.x = kmul * vld(&W_ih0[r * 2 + 0]);
    wx.y = kmul * vld(&W_ih0[r * 2 + 1]);
#pragma unroll
    for (int k = 0; k < 6; ++k) {
        whh0p[k].x = kmul * vld(&W_hh0[r * H + 2 * k]);
        whh0p[k].y = kmul * vld(&W_hh0[r * H + 2 * k + 1]);
        wih1p[k].x = kmul * vld(&W_ih1[r * H + 2 * k]);
        wih1p[k].y = kmul * vld(&W_ih1[r * H + 2 * k + 1]);
        whh1p[k].x = kmul * vld(&W_hh1[r * H + 2 * k]);
        whh1p[k].y = kmul * vld(&W_hh1[r * H + 2 * k + 1]);
    }
    f2 bias0p, bias1p;
    bias0p.x = kmul * (vld(&b_ih0[r]) + vld(&b_hh0[r])); bias0p.y = 0.0f;
    bias1p.x = kmul * (vld(&b_ih1[r]) + vld(&b_hh1[r])); bias1p.y = 0.0f;

    // ONE-TIME pre-loop pin: values now defined by opaque asm -> the
    // compiler cannot rematerialize them inside the loop.
    asm volatile("" : "+v"(wx),
                      "+v"(whh0p[0]), "+v"(whh0p[1]), "+v"(whh0p[2]),
                      "+v"(whh0p[3]), "+v"(whh0p[4]), "+v"(whh0p[5]),
                      "+v"(wih1p[0]), "+v"(wih1p[1]), "+v"(wih1p[2]),
                      "+v"(wih1p[3]), "+v"(wih1p[4]), "+v"(wih1p[5]),
                      "+v"(whh1p[0]), "+v"(whh1p[1]), "+v"(whh1p[2]),
                      "+v"(whh1p[3]), "+v"(whh1p[4]), "+v"(whh1p[5]),
                      "+v"(bias0p), "+v"(bias1p));

    // ---------------- state ----------------
    float c0 = 0.0f, c1 = 0.0f;
    f2 hp0[6], hq1[6];
#pragma unroll
    for (int k = 0; k < 6; ++k) { hp0[k] = (f2)(0.0f); hq1[k] = (f2)(0.0f); }

    const f4* xb4 = (const f4*)(x + (size_t)b * T * 2);
    f4 xq = xb4[0];

    auto step = [&](f2 xv) {
        // ---- layer 0: 3-chain packed dot (prescaled by kmul) ----
        f2 cA = pkfma(wx, xv, bias0p);
        cA = pkfma(whh0p[0], hp0[0], cA);
        cA = pkfma(whh0p[1], hp0[1], cA);
        f2 cB = pkmul(whh0p[2], hp0[2]);
        cB = pkfma(whh0p[3], hp0[3], cB);
        f2 cC = pkmul(whh0p[4], hp0[4]);
        cC = pkfma(whh0p[5], hp0[5], cC);
        cA = pkadd(cA, cB);
        cA = pkadd(cA, cC);
        const float s0 = fmaf(pre, rcp_(1.0f + exp2_(cA.x + cA.y)), pa);
        const float f0v = dppf<QP1>(s0);
        const float g0v = dppf<QP2>(s0);
        const float o0v = dppf<QP3>(s0);
        c0 = fmaf(f0v, c0, s0 * g0v);            // valid on gate-0 lanes
        const float h0v = o0v * fmaf(2.0f, rcp_(1.0f + exp2_(km2 * c0)), -1.0f);
        if (writer) *smw0 = h0v;                 // publish h0(t)

        // ---- layer 1: whh1 . h1(t-1) chains first (cover LDS round trip) ----
        f2 dA = pkfma(whh1p[0], hq1[0], bias1p);
        dA = pkfma(whh1p[1], hq1[1], dA);
        f2 dB = pkmul(whh1p[2], hq1[2]);
        dB = pkfma(whh1p[3], hq1[3], dB);
        f2 dC = pkmul(whh1p[4], hq1[4]);
        dC = pkfma(whh1p[5], hq1[5], dC);
        // vector readback of h0(t); fence pins load-after-store order
        memfence_();
        {
            const f4 r0 = *(const f4*)(smb + 0);
            const f4 r1 = *(const f4*)(smb + 4);
            const f4 r2 = *(const f4*)(smb + 8);
            hp0[0].x = r0.x; hp0[0].y = r0.y; hp0[1].x = r0.z; hp0[1].y = r0.w;
            hp0[2].x = r1.x; hp0[2].y = r1.y; hp0[3].x = r1.z; hp0[3].y = r1.w;
            hp0[4].x = r2.x; hp0[4].y = r2.y; hp0[5].x = r2.z; hp0[5].y = r2.w;
        }
        dA = pkfma(wih1p[0], hp0[0], dA);
        dA = pkfma(wih1p[1], hp0[1], dA);
        dB = pkfma(wih1p[2], hp0[2], dB);
        dB = pkfma(wih1p[3], hp0[3], dB);
        dC = pkfma(wih1p[4], hp0[4], dC);
        dC = pkfma(wih1p[5], hp0[5], dC);
        dA = pkadd(dA, dB);
        dA = pkadd(dA, dC);
        const float s1 = fmaf(pre, rcp_(1.0f + exp2_(dA.x + dA.y)), pa);
        const float f1v = dppf<QP1>(s1);
        const float g1v = dppf<QP2>(s1);
        const float o1v = dppf<QP3>(s1);
        c1 = fmaf(f1v, c1, s1 * g1v);
        const float h1v = o1v * fmaf(2.0f, rcp_(1.0f + exp2_(km2 * c1)), -1.0f);
        if (writer) *smw1 = h1v;                 // publish h1(t)
        memfence_();
        {
            const f4 q0 = *(const f4*)(smb + 16);
            const f4 q1 = *(const f4*)(smb + 20);
            const f4 q2 = *(const f4*)(smb + 24);
            hq1[0].x = q0.x; hq1[0].y = q0.y; hq1[1].x = q0.z; hq1[1].y = q0.w;
            hq1[2].x = q1.x; hq1[2].y = q1.y; hq1[3].x = q1.z; hq1[3].y = q1.w;
            hq1[4].x = q2.x; hq1[4].y = q2.y; hq1[5].x = q2.z; hq1[5].y = q2.w;
        }
    };

    for (int tt = 0; tt < T / 2 - 1; ++tt) {
        const f4 xn = xb4[tt + 1];               // prefetch next 2 steps of x
        f2 xa; xa.x = xq.x; xa.y = xq.y;
        step(xa);
        f2 xb; xb.x = xq.z; xb.y = xq.w;
        step(xb);
        xq = xn;
    }
    {   // peeled tail (no prefetch)
        f2 xa; xa.x = xq.x; xa.y = xq.y;
        step(xa);
        f2 xb; xb.x = xq.z; xb.y = xq.w;
        step(xb);
    }

    // ---------------- final FC (lane 0; hq1 holds h1(T-1) pairs) ----------------
    if (lane == 0) {
        float r0 = fc_b[0];
        float r1 = fc_b[1];
#pragma unroll
        for (int k = 0; k < 6; ++k) {
            r0 = fmaf(fc_W[2 * k],     hq1[k].x, r0);
            r0 = fmaf(fc_W[2 * k + 1], hq1[k].y, r0);
            r1 = fmaf(fc_W[H + 2 * k],     hq1[k].x, r1);
            r1 = fmaf(fc_W[H + 2 * k + 1], hq1[k].y, r1);
        }
        float2 res; res.x = r0; res.y = r1;
        *(float2*)(out + (size_t)b * 2) = res;
    }
}

extern "C" void kernel_launch(void* const* d_in, const int* in_sizes, int n_in,
                              void* d_out, int out_size, void* d_ws, size_t ws_size,
                              hipStream_t stream) {
    const float* x     = (const float*)d_in[0];
    const float* W_ih0 = (const float*)d_in[1];
    const float* W_hh0 = (const float*)d_in[2];
    const float* b_ih0 = (const float*)d_in[3];
    const float* b_hh0 = (const float*)d_in[4];
    const float* W_ih1 = (const float*)d_in[5];
    const float* W_hh1 = (const float*)d_in[6];
    const float* b_ih1 = (const float*)d_in[7];
    const float* b_hh1 = (const float*)d_in[8];
    const float* fc_W  = (const float*)d_in[9];
    const float* fc_b  = (const float*)d_in[10];
    float* out = (float*)d_out;

    // 4096 elements, 1 per wave, 4 waves per block -> 1024 blocks
    lstm2_fc_kernel<<<1024, 256, 0, stream>>>(
        x, W_ih0, W_hh0, b_ih0, b_hh0,
        W_ih1, W_hh1, b_ih1, b_hh1, fc_W, fc_b, out);
}

// Round 9
// 264.413 us; speedup vs baseline: 1.1288x; 1.1288x over previous
//
#include <hip/hip_runtime.h>

// LSTMModel: B=4096, T=512, IN=2, H=12, OUT=2, fp32.
// One batch element per wave64; lane = (unit u = lane>>2, gate = lane&3).
// 1024 blocks x 256 threads -> 4096 waves = 4 waves/SIMD.
// MERGED-ACTIVATION PIPELINE (r9): lanes 4u hold layer-0 (c0,h0) at step t,
// lanes 4u+1 hold layer-1 (c1,h1) lagged one step. One shared c-update +
// ONE tanh pass + ONE ds_write covers both layers (trans 8 -> 6 per step;
// trans issue ~quarter-rate is the revised dominant cost).
// DPP quad broadcasts (0x00/0x55/0xAA/0xFF) give every lane (i,f,g,o);
// 4 cndmasks select fresh-L0 vs stored-L1 per lane parity.
// h broadcast via per-wave private LDS (predicated writes, banks 0-11/16-27,
// conflict-free; plain f2 readback -- no extraction movs).

namespace {
constexpr int H  = 12;
constexpr int T  = 512;
constexpr float LOG2E = 1.4426950408889634f;

typedef float f2 __attribute__((ext_vector_type(2)));

__device__ __forceinline__ f2 pkfma(f2 a, f2 b, f2 c) {
    asm("v_pk_fma_f32 %0, %1, %2, %0" : "+v"(c) : "v"(a), "v"(b));
    return c;
}
__device__ __forceinline__ f2 pkmul(f2 a, f2 b) {
    f2 d; asm("v_pk_mul_f32 %0, %1, %2" : "=v"(d) : "v"(a), "v"(b)); return d;
}
__device__ __forceinline__ f2 pkadd(f2 a, f2 b) {
    f2 d; asm("v_pk_add_f32 %0, %1, %2" : "=v"(d) : "v"(a), "v"(b)); return d;
}
__device__ __forceinline__ float exp2_(float x) {
    float r; asm("v_exp_f32 %0, %1" : "=v"(r) : "v"(x)); return r;
}
__device__ __forceinline__ float rcp_(float x) { return __builtin_amdgcn_rcpf(x); }
__device__ __forceinline__ void memfence_() { asm volatile("" ::: "memory"); }

template <int CTRL>
__device__ __forceinline__ float dppf(float v) {
    return __int_as_float(__builtin_amdgcn_update_dpp(
        __float_as_int(v), __float_as_int(v), CTRL, 0xF, 0xF, true));
}
// quad_perm BROADCASTS: every lane of the quad reads quad-position k
constexpr int BC0 = 0x00;  // [0,0,0,0] -> i (gate-0 lane)
constexpr int BC1 = 0x55;  // [1,1,1,1] -> f
constexpr int BC2 = 0xAA;  // [2,2,2,2] -> g
constexpr int BC3 = 0xFF;  // [3,3,3,3] -> o

__device__ __forceinline__ float tanh_(float c) {
    // tanh(c) = 2/(1+2^(-2*log2e*c)) - 1 ; saturates correctly at +-1
    return fmaf(2.0f, rcp_(1.0f + exp2_(-2.0f * LOG2E * c)), -1.0f);
}
} // namespace

__global__ __launch_bounds__(256, 4) void lstm2_fc_kernel(
    const float* __restrict__ x,      // (4096, 512, 2)
    const float* __restrict__ W_ih0,  // (48, 2)
    const float* __restrict__ W_hh0,  // (48, 12)
    const float* __restrict__ b_ih0,  // (48)
    const float* __restrict__ b_hh0,  // (48)
    const float* __restrict__ W_ih1,  // (48, 12)
    const float* __restrict__ W_hh1,  // (48, 12)
    const float* __restrict__ b_ih1,  // (48)
    const float* __restrict__ b_hh1,  // (48)
    const float* __restrict__ fc_W,   // (2, 12)
    const float* __restrict__ fc_b,   // (2)
    float* __restrict__ out)          // (4096, 2)
{
    const int lane = threadIdx.x & 63;
    const int wid  = __builtin_amdgcn_readfirstlane((int)threadIdx.x >> 6);
    const int b    = blockIdx.x * 4 + wid;       // one element per wave
    const int u    = lane >> 2;                  // unit 0..15 (12 active)
    const int gate = lane & 3;                   // 0:i 1:f 2:g 3:o
    const int uc   = (u < H) ? u : 0;            // clamp idle lanes
    const int r    = gate * H + uc;              // weight row

    // sigmoid for i,f,o; tanh (=2*sigm(2x)-1) for g; exp2 prescale kmul
    // folded into weights & bias.
    const float pre  = (gate == 2) ? 2.0f : 1.0f;
    const float kmul = -LOG2E * pre;
    const float pa   = 1.0f - pre;

    // ---- per-wave private LDS: [0..11] h0 slots, [16..27] h1 slots ----
    __shared__ __align__(16) float sm[4 * 32];
    float* smb = &sm[wid * 32];
    const bool isL1 = (gate == 1);               // lane 4u+1 carries layer 1
    const bool pub  = (gate <= 1) && (u < H);    // publishers: gate0->h0, gate1->h1
    float* smw = smb + (isL1 ? 16 : 0) + uc;

    // ---------------- prescaled packed weights -> registers ----------------
    f2 wx, whh0p[6], wih1p[6], whh1p[6];
    wx.x = kmul * W_ih0[r * 2 + 0];
    wx.y = kmul * W_ih0[r * 2 + 1];
#pragma unroll
    for (int k = 0; k < 6; ++k) {
        whh0p[k].x = kmul * W_hh0[r * H + 2 * k];
        whh0p[k].y = kmul * W_hh0[r * H + 2 * k + 1];
        wih1p[k].x = kmul * W_ih1[r * H + 2 * k];
        wih1p[k].y = kmul * W_ih1[r * H + 2 * k + 1];
        whh1p[k].x = kmul * W_hh1[r * H + 2 * k];
        whh1p[k].y = kmul * W_hh1[r * H + 2 * k + 1];
    }
    f2 bias0p, bias1p;
    bias0p.x = kmul * (b_ih0[r] + b_hh0[r]); bias0p.y = 0.0f;
    bias1p.x = kmul * (b_ih1[r] + b_hh1[r]); bias1p.y = 0.0f;

    // ---------------- state ----------------
    // c: lanes 4u,4u+2,4u+3 evolve c0; lanes 4u+1 evolve c1 (lagged).
    float c = 0.0f;
    float I1s = 0.0f, F1s = 0.0f, G1s = 0.0f, O1s = 0.0f;  // stored s1 acts
    f2 hp0[6], hq1[6];                            // h0(t) / h1(t-1) pairs
#pragma unroll
    for (int k = 0; k < 6; ++k) { hp0[k] = (f2)(0.0f); hq1[k] = (f2)(0.0f); }

    const float* xp = x + (size_t)b * T * 2;      // wave-uniform pointer

    auto step = [&](float xv0, float xv1) {
        // ---- layer-0 dot (3 chains, prescaled by kmul) ----
        f2 xv; xv.x = xv0; xv.y = xv1;
        f2 cA = pkfma(wx, xv, bias0p);
        cA = pkfma(whh0p[0], hp0[0], cA);
        cA = pkfma(whh0p[1], hp0[1], cA);
        f2 cB = pkmul(whh0p[2], hp0[2]);
        cB = pkfma(whh0p[3], hp0[3], cB);
        f2 cC = pkmul(whh0p[4], hp0[4]);
        cC = pkfma(whh0p[5], hp0[5], cC);
        cA = pkadd(cA, pkadd(cB, cC));
        const float s0 = fmaf(pre, rcp_(1.0f + exp2_(cA.x + cA.y)), pa);
        // quad broadcasts: all lanes get (i,f,g,o) of their unit
        const float I0 = dppf<BC0>(s0);
        const float F0 = dppf<BC1>(s0);
        const float G0 = dppf<BC2>(s0);
        const float O0 = dppf<BC3>(s0);
        // ---- merged c-update + single tanh pass ----
        const float I = isL1 ? I1s : I0;
        const float F = isL1 ? F1s : F0;
        const float G = isL1 ? G1s : G0;
        const float O = isL1 ? O1s : O0;
        c = fmaf(F, c, I * G);                    // c0(t) on 4u / c1(t-1) on 4u+1
        const float hv = O * tanh_(c);            // h0(t) / h1(t-1)
        if (pub) *smw = hv;                       // ONE ds_write for both layers
        memfence_();                              // no hoisting reads above write
        // readback: h0(t) for L1 dot now + L0 dot next step; h1(t-1) for L1 dot
#pragma unroll
        for (int k = 0; k < 6; ++k) hp0[k] = *(const f2*)(smb + 2 * k);
#pragma unroll
        for (int k = 0; k < 6; ++k) hq1[k] = *(const f2*)(smb + 16 + 2 * k);
        // ---- layer-1 dot (3 chains, interleaved whh1/wih1) ----
        f2 dA = pkfma(whh1p[0], hq1[0], bias1p);
        dA = pkfma(wih1p[0], hp0[0], dA);
        dA = pkfma(whh1p[1], hq1[1], dA);
        dA = pkfma(wih1p[1], hp0[1], dA);
        f2 dB = pkmul(whh1p[2], hq1[2]);
        dB = pkfma(wih1p[2], hp0[2], dB);
        dB = pkfma(whh1p[3], hq1[3], dB);
        dB = pkfma(wih1p[3], hp0[3], dB);
        f2 dC = pkmul(whh1p[4], hq1[4]);
        dC = pkfma(wih1p[4], hp0[4], dC);
        dC = pkfma(whh1p[5], hq1[5], dC);
        dC = pkfma(wih1p[5], hp0[5], dC);
        dA = pkadd(dA, pkadd(dB, dC));
        const float s1 = fmaf(pre, rcp_(1.0f + exp2_(dA.x + dA.y)), pa);
        // store s1 acts (consumed at next step's merged update)
        I1s = dppf<BC0>(s1);
        F1s = dppf<BC1>(s1);
        G1s = dppf<BC2>(s1);
        O1s = dppf<BC3>(s1);
    };

    float2 xc = *(const float2*)xp;
    for (int t = 0; t < T - 1; ++t) {
        const float2 xn = *(const float2*)(xp + 2 * (t + 1));  // prefetch
        step(xc.x, xc.y);
        xc = xn;
    }
    step(xc.x, xc.y);

    // ---- epilogue: finish the lagged layer-1 update for t = T-1 ----
    {
        const float cE = fmaf(F1s, c, I1s * G1s);   // c1(T-1) on gate-1 lanes
        const float hE = O1s * tanh_(cE);
        if (pub && isL1) *smw = hE;                 // publish h1(T-1)
        memfence_();
    }

    // ---------------- final FC (lane 0) ----------------
    if (lane == 0) {
        float r0 = fc_b[0];
        float r1 = fc_b[1];
#pragma unroll
        for (int j = 0; j < H; ++j) {
            const float hj = smb[16 + j];
            r0 = fmaf(fc_W[j],     hj, r0);
            r1 = fmaf(fc_W[H + j], hj, r1);
        }
        float2 res; res.x = r0; res.y = r1;
        *(float2*)(out + (size_t)b * 2) = res;
    }
}

extern "C" void kernel_launch(void* const* d_in, const int* in_sizes, int n_in,
                              void* d_out, int out_size, void* d_ws, size_t ws_size,
                              hipStream_t stream) {
    const float* x     = (const float*)d_in[0];
    const float* W_ih0 = (const float*)d_in[1];
    const float* W_hh0 = (const float*)d_in[2];
    const float* b_ih0 = (const float*)d_in[3];
    const float* b_hh0 = (const float*)d_in[4];
    const float* W_ih1 = (const float*)d_in[5];
    const float* W_hh1 = (const float*)d_in[6];
    const float* b_ih1 = (const float*)d_in[7];
    const float* b_hh1 = (const float*)d_in[8];
    const float* fc_W  = (const float*)d_in[9];
    const float* fc_b  = (const float*)d_in[10];
    float* out = (float*)d_out;

    // 4096 elements, 1 per wave, 4 waves per block -> 1024 blocks
    lstm2_fc_kernel<<<1024, 256, 0, stream>>>(
        x, W_ih0, W_hh0, b_ih0, b_hh0,
        W_ih1, W_hh1, b_ih1, b_hh1, fc_W, fc_b, out);
}

// Round 10
// 252.763 us; speedup vs baseline: 1.1808x; 1.0461x over previous
//
#include <hip/hip_runtime.h>

// LSTMModel: B=4096, T=512, IN=2, H=12, OUT=2, fp32.
// One batch element per wave64; lane = (unit u = lane>>2, gate = lane&3).
// 1024 blocks x 256 threads -> 4096 waves = 4 waves/SIMD.
// r10: SAME structure as r9 (merged activation pipeline, lanes 4u+1 carry
// layer-1 lagged one step; one c-update + one tanh + one ds_write per step)
// but ALL packed math is plain C++ ext-vector ops -> clang emits native
// v_pk_fma_f32 with NO inline-asm register-pair/tied-operand constraints.
// Theory: r4-r9's ~80 phantom VALU instr/step were allocator shuffle-movs
// forced by 31 constrained asm statements per iteration.

namespace {
constexpr int H  = 12;
constexpr int T  = 512;
constexpr float LOG2E = 1.4426950408889634f;

typedef float f2 __attribute__((ext_vector_type(2)));

__device__ __forceinline__ f2 fma2(f2 a, f2 b, f2 c) {
    return __builtin_elementwise_fma(a, b, c);
}
__device__ __forceinline__ float exp2_(float x) {
    float r; asm("v_exp_f32 %0, %1" : "=v"(r) : "v"(x)); return r;
}
__device__ __forceinline__ float rcp_(float x) { return __builtin_amdgcn_rcpf(x); }
__device__ __forceinline__ void memfence_() { asm volatile("" ::: "memory"); }

template <int CTRL>
__device__ __forceinline__ float dppf(float v) {
    return __int_as_float(__builtin_amdgcn_update_dpp(
        __float_as_int(v), __float_as_int(v), CTRL, 0xF, 0xF, true));
}
// quad_perm BROADCASTS: every lane of the quad reads quad-position k
constexpr int BC0 = 0x00;  // [0,0,0,0] -> i
constexpr int BC1 = 0x55;  // [1,1,1,1] -> f
constexpr int BC2 = 0xAA;  // [2,2,2,2] -> g
constexpr int BC3 = 0xFF;  // [3,3,3,3] -> o

__device__ __forceinline__ float tanh_(float c) {
    // tanh(c) = 2/(1+2^(-2*log2e*c)) - 1 ; saturates correctly at +-1
    return fmaf(2.0f, rcp_(1.0f + exp2_(-2.0f * LOG2E * c)), -1.0f);
}
} // namespace

__global__ __launch_bounds__(256, 4) void lstm2_fc_kernel(
    const float* __restrict__ x,      // (4096, 512, 2)
    const float* __restrict__ W_ih0,  // (48, 2)
    const float* __restrict__ W_hh0,  // (48, 12)
    const float* __restrict__ b_ih0,  // (48)
    const float* __restrict__ b_hh0,  // (48)
    const float* __restrict__ W_ih1,  // (48, 12)
    const float* __restrict__ W_hh1,  // (48, 12)
    const float* __restrict__ b_ih1,  // (48)
    const float* __restrict__ b_hh1,  // (48)
    const float* __restrict__ fc_W,   // (2, 12)
    const float* __restrict__ fc_b,   // (2)
    float* __restrict__ out)          // (4096, 2)
{
    const int lane = threadIdx.x & 63;
    const int wid  = __builtin_amdgcn_readfirstlane((int)threadIdx.x >> 6);
    const int b    = blockIdx.x * 4 + wid;       // one element per wave
    const int u    = lane >> 2;                  // unit 0..15 (12 active)
    const int gate = lane & 3;                   // 0:i 1:f 2:g 3:o
    const int uc   = (u < H) ? u : 0;            // clamp idle lanes
    const int r    = gate * H + uc;              // weight row

    // sigmoid for i,f,o; tanh (=2*sigm(2x)-1) for g; exp2 prescale kmul
    // folded into weights & bias.
    const float pre  = (gate == 2) ? 2.0f : 1.0f;
    const float kmul = -LOG2E * pre;
    const float pa   = 1.0f - pre;

    // ---- per-wave private LDS: [0..11] h0 slots, [16..27] h1 slots ----
    __shared__ __align__(16) float sm[4 * 32];
    float* smb = &sm[wid * 32];
    const bool isL1 = (gate == 1);               // lane 4u+1 carries layer 1
    const bool pub  = (gate <= 1) && (u < H);    // gate0 -> h0, gate1 -> h1
    float* smw = smb + (isL1 ? 16 : 0) + uc;

    // ---------------- prescaled packed weights -> registers ----------------
    f2 wx, whh0p[6], wih1p[6], whh1p[6];
    wx.x = kmul * W_ih0[r * 2 + 0];
    wx.y = kmul * W_ih0[r * 2 + 1];
#pragma unroll
    for (int k = 0; k < 6; ++k) {
        whh0p[k].x = kmul * W_hh0[r * H + 2 * k];
        whh0p[k].y = kmul * W_hh0[r * H + 2 * k + 1];
        wih1p[k].x = kmul * W_ih1[r * H + 2 * k];
        wih1p[k].y = kmul * W_ih1[r * H + 2 * k + 1];
        whh1p[k].x = kmul * W_hh1[r * H + 2 * k];
        whh1p[k].y = kmul * W_hh1[r * H + 2 * k + 1];
    }
    f2 bias0p, bias1p;
    bias0p.x = kmul * (b_ih0[r] + b_hh0[r]); bias0p.y = 0.0f;
    bias1p.x = kmul * (b_ih1[r] + b_hh1[r]); bias1p.y = 0.0f;

    // ---------------- state ----------------
    float c = 0.0f;                               // c0 on gate-0 / c1 on gate-1
    float I1s = 0.0f, F1s = 0.0f, G1s = 0.0f, O1s = 0.0f;  // stored s1 acts
    f2 hp0[6], hq1[6];                            // h0(t) / h1(t-1) pairs
#pragma unroll
    for (int k = 0; k < 6; ++k) { hp0[k] = (f2)(0.0f); hq1[k] = (f2)(0.0f); }

    const float* xp = x + (size_t)b * T * 2;      // wave-uniform pointer

    auto step = [&](float xv0, float xv1) {
        // ---- layer-0 dot (3 chains, prescaled by kmul) ----
        f2 xv; xv.x = xv0; xv.y = xv1;
        f2 cA = fma2(wx, xv, bias0p);
        cA = fma2(whh0p[0], hp0[0], cA);
        cA = fma2(whh0p[1], hp0[1], cA);
        f2 cB = whh0p[2] * hp0[2];
        cB = fma2(whh0p[3], hp0[3], cB);
        f2 cC = whh0p[4] * hp0[4];
        cC = fma2(whh0p[5], hp0[5], cC);
        cA = cA + cB + cC;
        const float s0 = fmaf(pre, rcp_(1.0f + exp2_(cA.x + cA.y)), pa);
        // quad broadcasts: all lanes get (i,f,g,o) of their unit
        const float I0 = dppf<BC0>(s0);
        const float F0 = dppf<BC1>(s0);
        const float G0 = dppf<BC2>(s0);
        const float O0 = dppf<BC3>(s0);
        // ---- merged c-update + single tanh pass ----
        const float I = isL1 ? I1s : I0;
        const float F = isL1 ? F1s : F0;
        const float G = isL1 ? G1s : G0;
        const float O = isL1 ? O1s : O0;
        c = fmaf(F, c, I * G);                    // c0(t) / c1(t-1)
        const float hv = O * tanh_(c);            // h0(t) / h1(t-1)
        if (pub) *smw = hv;                       // ONE ds_write for both layers
        memfence_();                              // no hoisting reads above write
#pragma unroll
        for (int k = 0; k < 6; ++k) hp0[k] = *(const f2*)(smb + 2 * k);
#pragma unroll
        for (int k = 0; k < 6; ++k) hq1[k] = *(const f2*)(smb + 16 + 2 * k);
        // ---- layer-1 dot (3 chains, interleaved whh1/wih1) ----
        f2 dA = fma2(whh1p[0], hq1[0], bias1p);
        dA = fma2(wih1p[0], hp0[0], dA);
        dA = fma2(whh1p[1], hq1[1], dA);
        dA = fma2(wih1p[1], hp0[1], dA);
        f2 dB = whh1p[2] * hq1[2];
        dB = fma2(wih1p[2], hp0[2], dB);
        dB = fma2(whh1p[3], hq1[3], dB);
        dB = fma2(wih1p[3], hp0[3], dB);
        f2 dC = whh1p[4] * hq1[4];
        dC = fma2(wih1p[4], hp0[4], dC);
        dC = fma2(whh1p[5], hq1[5], dC);
        dC = fma2(wih1p[5], hp0[5], dC);
        dA = dA + dB + dC;
        const float s1 = fmaf(pre, rcp_(1.0f + exp2_(dA.x + dA.y)), pa);
        // store s1 acts (consumed at next step's merged update)
        I1s = dppf<BC0>(s1);
        F1s = dppf<BC1>(s1);
        G1s = dppf<BC2>(s1);
        O1s = dppf<BC3>(s1);
    };

    float2 xc = *(const float2*)xp;
    for (int t = 0; t < T - 1; ++t) {
        const float2 xn = *(const float2*)(xp + 2 * (t + 1));  // prefetch
        step(xc.x, xc.y);
        xc = xn;
    }
    step(xc.x, xc.y);

    // ---- epilogue: finish the lagged layer-1 update for t = T-1 ----
    {
        const float cE = fmaf(F1s, c, I1s * G1s);   // c1(T-1) on gate-1 lanes
        const float hE = O1s * tanh_(cE);
        if (pub && isL1) *smw = hE;                 // publish h1(T-1)
        memfence_();
    }

    // ---------------- final FC (lane 0) ----------------
    if (lane == 0) {
        float r0 = fc_b[0];
        float r1 = fc_b[1];
#pragma unroll
        for (int j = 0; j < H; ++j) {
            const float hj = smb[16 + j];
            r0 = fmaf(fc_W[j],     hj, r0);
            r1 = fmaf(fc_W[H + j], hj, r1);
        }
        float2 res; res.x = r0; res.y = r1;
        *(float2*)(out + (size_t)b * 2) = res;
    }
}

extern "C" void kernel_launch(void* const* d_in, const int* in_sizes, int n_in,
                              void* d_out, int out_size, void* d_ws, size_t ws_size,
                              hipStream_t stream) {
    const float* x     = (const float*)d_in[0];
    const float* W_ih0 = (const float*)d_in[1];
    const float* W_hh0 = (const float*)d_in[2];
    const float* b_ih0 = (const float*)d_in[3];
    const float* b_hh0 = (const float*)d_in[4];
    const float* W_ih1 = (const float*)d_in[5];
    const float* W_hh1 = (const float*)d_in[6];
    const float* b_ih1 = (const float*)d_in[7];
    const float* b_hh1 = (const float*)d_in[8];
    const float* fc_W  = (const float*)d_in[9];
    const float* fc_b  = (const float*)d_in[10];
    float* out = (float*)d_out;

    // 4096 elements, 1 per wave, 4 waves per block -> 1024 blocks
    lstm2_fc_kernel<<<1024, 256, 0, stream>>>(
        x, W_ih0, W_hh0, b_ih0, b_hh0,
        W_ih1, W_hh1, b_ih1, b_hh1, fc_W, fc_b, out);
}

// Round 11
// 252.492 us; speedup vs baseline: 1.1820x; 1.0011x over previous
//
#include <hip/hip_runtime.h>

// LSTMModel: B=4096, T=512, IN=2, H=12, OUT=2, fp32.
// One batch element per wave64; lane = (unit u = lane>>2, gate = lane&3).
// 1024 blocks x 256 threads -> 4096 waves = 4 waves/SIMD.
// r11: IDENTICAL to r10 except amdgpu_waves_per_eu(4,4): r1-r10 showed the
// allocator targets MAX occupancy (8 waves -> 64/36 VGPR) and remats the
// whole weight set every step (phantom ~1.7x VALU issue), even though we
// only launch 4 waves/SIMD. Pinning min=max=4 gives a 128-VGPR budget with
// no incentive to shrink -> weights become truly register-resident.

namespace {
constexpr int H  = 12;
constexpr int T  = 512;
constexpr float LOG2E = 1.4426950408889634f;

typedef float f2 __attribute__((ext_vector_type(2)));

__device__ __forceinline__ f2 fma2(f2 a, f2 b, f2 c) {
    return __builtin_elementwise_fma(a, b, c);
}
__device__ __forceinline__ float exp2_(float x) {
    float r; asm("v_exp_f32 %0, %1" : "=v"(r) : "v"(x)); return r;
}
__device__ __forceinline__ float rcp_(float x) { return __builtin_amdgcn_rcpf(x); }
__device__ __forceinline__ void memfence_() { asm volatile("" ::: "memory"); }

template <int CTRL>
__device__ __forceinline__ float dppf(float v) {
    return __int_as_float(__builtin_amdgcn_update_dpp(
        __float_as_int(v), __float_as_int(v), CTRL, 0xF, 0xF, true));
}
// quad_perm BROADCASTS: every lane of the quad reads quad-position k
constexpr int BC0 = 0x00;  // [0,0,0,0] -> i
constexpr int BC1 = 0x55;  // [1,1,1,1] -> f
constexpr int BC2 = 0xAA;  // [2,2,2,2] -> g
constexpr int BC3 = 0xFF;  // [3,3,3,3] -> o

__device__ __forceinline__ float tanh_(float c) {
    // tanh(c) = 2/(1+2^(-2*log2e*c)) - 1 ; saturates correctly at +-1
    return fmaf(2.0f, rcp_(1.0f + exp2_(-2.0f * LOG2E * c)), -1.0f);
}
} // namespace

__global__
__attribute__((amdgpu_flat_work_group_size(256, 256)))
__attribute__((amdgpu_waves_per_eu(4, 4)))
void lstm2_fc_kernel(
    const float* __restrict__ x,      // (4096, 512, 2)
    const float* __restrict__ W_ih0,  // (48, 2)
    const float* __restrict__ W_hh0,  // (48, 12)
    const float* __restrict__ b_ih0,  // (48)
    const float* __restrict__ b_hh0,  // (48)
    const float* __restrict__ W_ih1,  // (48, 12)
    const float* __restrict__ W_hh1,  // (48, 12)
    const float* __restrict__ b_ih1,  // (48)
    const float* __restrict__ b_hh1,  // (48)
    const float* __restrict__ fc_W,   // (2, 12)
    const float* __restrict__ fc_b,   // (2)
    float* __restrict__ out)          // (4096, 2)
{
    const int lane = threadIdx.x & 63;
    const int wid  = __builtin_amdgcn_readfirstlane((int)threadIdx.x >> 6);
    const int b    = blockIdx.x * 4 + wid;       // one element per wave
    const int u    = lane >> 2;                  // unit 0..15 (12 active)
    const int gate = lane & 3;                   // 0:i 1:f 2:g 3:o
    const int uc   = (u < H) ? u : 0;            // clamp idle lanes
    const int r    = gate * H + uc;              // weight row

    // sigmoid for i,f,o; tanh (=2*sigm(2x)-1) for g; exp2 prescale kmul
    // folded into weights & bias.
    const float pre  = (gate == 2) ? 2.0f : 1.0f;
    const float kmul = -LOG2E * pre;
    const float pa   = 1.0f - pre;

    // ---- per-wave private LDS: [0..11] h0 slots, [16..27] h1 slots ----
    __shared__ __align__(16) float sm[4 * 32];
    float* smb = &sm[wid * 32];
    const bool isL1 = (gate == 1);               // lane 4u+1 carries layer 1
    const bool pub  = (gate <= 1) && (u < H);    // gate0 -> h0, gate1 -> h1
    float* smw = smb + (isL1 ? 16 : 0) + uc;

    // ---------------- prescaled packed weights -> registers ----------------
    f2 wx, whh0p[6], wih1p[6], whh1p[6];
    wx.x = kmul * W_ih0[r * 2 + 0];
    wx.y = kmul * W_ih0[r * 2 + 1];
#pragma unroll
    for (int k = 0; k < 6; ++k) {
        whh0p[k].x = kmul * W_hh0[r * H + 2 * k];
        whh0p[k].y = kmul * W_hh0[r * H + 2 * k + 1];
        wih1p[k].x = kmul * W_ih1[r * H + 2 * k];
        wih1p[k].y = kmul * W_ih1[r * H + 2 * k + 1];
        whh1p[k].x = kmul * W_hh1[r * H + 2 * k];
        whh1p[k].y = kmul * W_hh1[r * H + 2 * k + 1];
    }
    f2 bias0p, bias1p;
    bias0p.x = kmul * (b_ih0[r] + b_hh0[r]); bias0p.y = 0.0f;
    bias1p.x = kmul * (b_ih1[r] + b_hh1[r]); bias1p.y = 0.0f;

    // ---------------- state ----------------
    float c = 0.0f;                               // c0 on gate-0 / c1 on gate-1
    float I1s = 0.0f, F1s = 0.0f, G1s = 0.0f, O1s = 0.0f;  // stored s1 acts
    f2 hp0[6], hq1[6];                            // h0(t) / h1(t-1) pairs
#pragma unroll
    for (int k = 0; k < 6; ++k) { hp0[k] = (f2)(0.0f); hq1[k] = (f2)(0.0f); }

    const float* xp = x + (size_t)b * T * 2;      // wave-uniform pointer

    auto step = [&](float xv0, float xv1) {
        // ---- layer-0 dot (3 chains, prescaled by kmul) ----
        f2 xv; xv.x = xv0; xv.y = xv1;
        f2 cA = fma2(wx, xv, bias0p);
        cA = fma2(whh0p[0], hp0[0], cA);
        cA = fma2(whh0p[1], hp0[1], cA);
        f2 cB = whh0p[2] * hp0[2];
        cB = fma2(whh0p[3], hp0[3], cB);
        f2 cC = whh0p[4] * hp0[4];
        cC = fma2(whh0p[5], hp0[5], cC);
        cA = cA + cB + cC;
        const float s0 = fmaf(pre, rcp_(1.0f + exp2_(cA.x + cA.y)), pa);
        // quad broadcasts: all lanes get (i,f,g,o) of their unit
        const float I0 = dppf<BC0>(s0);
        const float F0 = dppf<BC1>(s0);
        const float G0 = dppf<BC2>(s0);
        const float O0 = dppf<BC3>(s0);
        // ---- merged c-update + single tanh pass ----
        const float I = isL1 ? I1s : I0;
        const float F = isL1 ? F1s : F0;
        const float G = isL1 ? G1s : G0;
        const float O = isL1 ? O1s : O0;
        c = fmaf(F, c, I * G);                    // c0(t) / c1(t-1)
        const float hv = O * tanh_(c);            // h0(t) / h1(t-1)
        if (pub) *smw = hv;                       // ONE ds_write for both layers
        memfence_();                              // no hoisting reads above write
#pragma unroll
        for (int k = 0; k < 6; ++k) hp0[k] = *(const f2*)(smb + 2 * k);
#pragma unroll
        for (int k = 0; k < 6; ++k) hq1[k] = *(const f2*)(smb + 16 + 2 * k);
        // ---- layer-1 dot (3 chains, interleaved whh1/wih1) ----
        f2 dA = fma2(whh1p[0], hq1[0], bias1p);
        dA = fma2(wih1p[0], hp0[0], dA);
        dA = fma2(whh1p[1], hq1[1], dA);
        dA = fma2(wih1p[1], hp0[1], dA);
        f2 dB = whh1p[2] * hq1[2];
        dB = fma2(wih1p[2], hp0[2], dB);
        dB = fma2(whh1p[3], hq1[3], dB);
        dB = fma2(wih1p[3], hp0[3], dB);
        f2 dC = whh1p[4] * hq1[4];
        dC = fma2(wih1p[4], hp0[4], dC);
        dC = fma2(whh1p[5], hq1[5], dC);
        dC = fma2(wih1p[5], hp0[5], dC);
        dA = dA + dB + dC;
        const float s1 = fmaf(pre, rcp_(1.0f + exp2_(dA.x + dA.y)), pa);
        // store s1 acts (consumed at next step's merged update)
        I1s = dppf<BC0>(s1);
        F1s = dppf<BC1>(s1);
        G1s = dppf<BC2>(s1);
        O1s = dppf<BC3>(s1);
    };

    float2 xc = *(const float2*)xp;
    for (int t = 0; t < T - 1; ++t) {
        const float2 xn = *(const float2*)(xp + 2 * (t + 1));  // prefetch
        step(xc.x, xc.y);
        xc = xn;
    }
    step(xc.x, xc.y);

    // ---- epilogue: finish the lagged layer-1 update for t = T-1 ----
    {
        const float cE = fmaf(F1s, c, I1s * G1s);   // c1(T-1) on gate-1 lanes
        const float hE = O1s * tanh_(cE);
        if (pub && isL1) *smw = hE;                 // publish h1(T-1)
        memfence_();
    }

    // ---------------- final FC (lane 0) ----------------
    if (lane == 0) {
        float r0 = fc_b[0];
        float r1 = fc_b[1];
#pragma unroll
        for (int j = 0; j < H; ++j) {
            const float hj = smb[16 + j];
            r0 = fmaf(fc_W[j],     hj, r0);
            r1 = fmaf(fc_W[H + j], hj, r1);
        }
        float2 res; res.x = r0; res.y = r1;
        *(float2*)(out + (size_t)b * 2) = res;
    }
}

extern "C" void kernel_launch(void* const* d_in, const int* in_sizes, int n_in,
                              void* d_out, int out_size, void* d_ws, size_t ws_size,
                              hipStream_t stream) {
    const float* x     = (const float*)d_in[0];
    const float* W_ih0 = (const float*)d_in[1];
    const float* W_hh0 = (const float*)d_in[2];
    const float* b_ih0 = (const float*)d_in[3];
    const float* b_hh0 = (const float*)d_in[4];
    const float* W_ih1 = (const float*)d_in[5];
    const float* W_hh1 = (const float*)d_in[6];
    const float* b_ih1 = (const float*)d_in[7];
    const float* b_hh1 = (const float*)d_in[8];
    const float* fc_W  = (const float*)d_in[9];
    const float* fc_b  = (const float*)d_in[10];
    float* out = (float*)d_out;

    // 4096 elements, 1 per wave, 4 waves per block -> 1024 blocks
    lstm2_fc_kernel<<<1024, 256, 0, stream>>>(
        x, W_ih0, W_hh0, b_ih0, b_hh0,
        W_ih1, W_hh1, b_ih1, b_hh1, fc_W, fc_b, out);
}